// Round 15
// baseline (203.256 us; speedup 1.0000x reference)
//
#include <hip/hip_runtime.h>

// GNN surrogate — ALL-REGISTER MFMA chain, zero LDS (r15).
// Key insight: for mfma_f32_16x16x16_f16 (K=16), the C-frag layout
// [row=quad*4+r][col=lane&15] is identical to the A/B operand layout
// [k=quad*4+j][m|n=lane&15]. A pk4'd C-frag IS the next stage's operand:
// as B it contracts its rows; as A it represents its transpose. Orientations
// chosen so every stage contracts the predecessor's ROW dim:
//   L0: T0[node][fout] = x·W0          (rows=node)
//   G:  P^T[fout][node_i] = sum_j mfma(A=T-frag (transpose), B=adj-tile)
//   L:  T'[node][fout'] = sum_t mfma(A=P-frag (transpose), B=Meff-tile)
// -> the entire batch lives in VGPRs; no LDS, no barriers. adj is
// pre-swizzled in ws so each G tile-pair is one global b128 load (L1-hot).
// Folds (exact): M_l = W2[l]@W1[l+1] (adj row-normalized -> biases commute),
// lift into W1eff (K=3 pad 16), v, u, cp as before.

typedef _Float16 f16;
typedef __attribute__((ext_vector_type(8))) _Float16 half8;
typedef __attribute__((ext_vector_type(4))) _Float16 half4;
typedef __attribute__((ext_vector_type(2))) __fp16 fp16x2;   // cvt_pkrtz native
typedef __attribute__((ext_vector_type(4))) float f32x4;

namespace {
constexpr int N = 128, H = 32;
// ws byte layout
constexpr int WS_ADJB = 0;       // f16 swizzled adj tiles [8g][4p][64lane][8] (32768 B)
constexpr int WS_W0B  = 32768;   // f16 [2t][64lane][4]  W1eff B-tiles       (1024 B)
constexpr int WS_MB   = 33792;   // f16 [2l][2t][2tp][64][4] Meff B-tiles    (4096 B)
constexpr int WS_BIAS = 37888;   // f32 [3][32] folded biases                 (384 B)
constexpr int WS_V    = 38400;   // f32 [128]                                 (512 B)
constexpr int WS_U    = 38912;   // f32 [32]                                  (128 B)
constexpr int WS_C    = 39040;   // f32 [1]
}

static __device__ __forceinline__ half4 pk4(float a, float b, float c, float d) {
  union { half4 v; fp16x2 h[2]; } u;
  u.h[0] = __builtin_amdgcn_cvt_pkrtz(a, b);
  u.h[1] = __builtin_amdgcn_cvt_pkrtz(c, d);
  return u.v;
}
static __device__ __forceinline__ half4 relupk(f32x4 c) {
  const half4 z = {};
  return __builtin_elementwise_max(pk4(c[0], c[1], c[2], c[3]), z);
}
static __device__ __forceinline__ half4 pkc(f32x4 c) {
  return pk4(c[0], c[1], c[2], c[3]);
}

// ---- single-block prep: swizzled adj tiles, B-layout weights, folds ----
__global__ void prep(const float* __restrict__ adj,
                     const float* __restrict__ W_lift,
                     const float* __restrict__ b_lift,
                     const float* __restrict__ W1,
                     const float* __restrict__ b1,
                     const float* __restrict__ W2,
                     const float* __restrict__ b2,
                     const float* __restrict__ W_ro,
                     const float* __restrict__ b_ro,
                     char* __restrict__ ws) {
  const int tid = threadIdx.x;
  f16* adjb  = (f16*)(ws + WS_ADJB);
  f16* w0b   = (f16*)(ws + WS_W0B);
  f16* mb    = (f16*)(ws + WS_MB);
  float* bia = (float*)(ws + WS_BIAS);
  float* v   = (float*)(ws + WS_V);
  float* u   = (float*)(ws + WS_U);
  float* cp  = (float*)(ws + WS_C);

  // adj tiles: entry e=(g,p,lane): 8 f16 = B-tiles jt=2p,2p+1 for output gi=g
  // value[h*4+jj] = adj[g*16+lrow][(2p+h)*16 + quad*4 + jj]
  for (int e = tid; e < 2048; e += 256) {
    const int g = e >> 8, p = (e >> 6) & 3, lane = e & 63;
    const int lr = lane & 15, q = lane >> 4;
    const float* src = adj + (g * 16 + lr) * N;
    f16* dst = adjb + e * 8;
#pragma unroll
    for (int h = 0; h < 2; ++h)
#pragma unroll
      for (int jj = 0; jj < 4; ++jj)
        dst[h * 4 + jj] = (f16)src[(2 * p + h) * 16 + q * 4 + jj];
  }

  __shared__ float tmp[3][H][H];
  __shared__ float sred[N];
  for (int idx = tid; idx < 3 * H * H; idx += 256) {
    const int l = idx >> 10, rem = idx & 1023;
    const int k = rem >> 5, fo = rem & 31;
    float val = 0.f;
    if (l == 0) {
      if (k < 3) for (int c = 0; c < H; ++c) val += W_lift[k * H + c] * W1[c * H + fo];
    } else {
      const float* w2l = W2 + (l - 1) * H * H;
      const float* w1n = W1 + l * H * H;
      for (int c = 0; c < H; ++c) val += w2l[k * H + c] * w1n[c * H + fo];
    }
    tmp[l][k][fo] = val;
  }
  if (tid < N) {
    float s = 0.f;
    for (int i = 0; i < N; ++i) s += adj[i * N + tid];
    v[tid] = s * (1.0f / N);
    sred[tid] = s * (1.0f / N);
  }
  if (tid < H) {
    float s0 = b1[tid], s1 = b1[H + tid], s2 = b1[2 * H + tid];
    for (int c = 0; c < H; ++c) {
      s0 += b_lift[c] * W1[c * H + tid];
      s1 += b2[c] * W1[H * H + c * H + tid];
      s2 += b2[H + c] * W1[2 * H * H + c * H + tid];
    }
    bia[tid] = s0; bia[H + tid] = s1; bia[2 * H + tid] = s2;
    float su = 0.f;
    for (int c = 0; c < H; ++c) su += W2[2 * H * H + tid * H + c] * W_ro[c];
    u[tid] = su;
  }
  __syncthreads();
  // W0B[t][lane][j] = W1eff[quad*4+j][t*16+lrow]  (B-layout)
  for (int e = tid; e < 512; e += 256) {
    const int t = e >> 8, lane = (e >> 2) & 63, j = e & 3;
    const int lr = lane & 15, q = lane >> 4;
    w0b[e] = (f16)tmp[0][q * 4 + j][t * 16 + lr];
  }
  // MB[l][t][tp][lane][j] = Meff_{l+1}[t*16+quad*4+j][tp*16+lrow]
  for (int e = tid; e < 2048; e += 256) {
    const int l = e >> 10, rem = e & 1023;
    const int t = rem >> 9, tp = (rem >> 8) & 1, lane = (rem >> 2) & 63, j = rem & 3;
    const int lr = lane & 15, q = lane >> 4;
    mb[e] = (f16)tmp[1 + l][t * 16 + q * 4 + j][tp * 16 + lr];
  }
  if (tid == 0) {
    float c2r = 0.f;
    for (int k = 0; k < H; ++k) c2r += b2[2 * H + k] * W_ro[k];
    float S = 0.f;
    for (int j = 0; j < N; ++j) S += sred[j];
    cp[0] = c2r * S + b_ro[0];
  }
}

__global__ __launch_bounds__(256, 3)
void gnn_mfma(const float* __restrict__ x,
              const char* __restrict__ ws,
              float* __restrict__ out) {
  const f16* adjb  = (const f16*)(ws + WS_ADJB);
  const f16* w0b   = (const f16*)(ws + WS_W0B);
  const f16* mb    = (const f16*)(ws + WS_MB);
  const float* bia = (const float*)(ws + WS_BIAS);
  const float* v   = (const float*)(ws + WS_V);
  const float* u   = (const float*)(ws + WS_U);
  const float* cp  = (const float*)(ws + WS_C);

  const int tid  = threadIdx.x;
  const int wave = tid >> 6;
  const int lane = tid & 63;
  const int lrow = lane & 15;
  const int quad = lane >> 4;
  const int b    = blockIdx.x * 4 + wave;

  const f32x4 zero = {0.f, 0.f, 0.f, 0.f};

  half4 tf[8][2];   // current T state (rows=node, cols=fout), f16 operand form
  half4 pf[2][8];   // current P state (rows=fout, cols=node), f16 operand form

  // ---- L0: T0[node][fout] = relu(x·W1eff + b0) ----
  {
    const half4 w0 = *(const half4*)(w0b + (0 * 64 + lane) * 4);
    const half4 w1 = *(const half4*)(w0b + (1 * 64 + lane) * 4);
    const float bb0 = bia[lrow], bb1 = bia[16 + lrow];   // bias per fout=col
    const f32x4 bi0 = {bb0, bb0, bb0, bb0};
    const f32x4 bi1 = {bb1, bb1, bb1, bb1};
#pragma unroll
    for (int g = 0; g < 8; ++g) {
      half4 xa = {};
      if (quad == 0) {   // A[m=node=lrow][k=fin=quad*4+j]: fin 0..2 live
        const float* xr = x + ((size_t)b * N + g * 16 + lrow) * 3;
        union { half4 v4; fp16x2 p[2]; } xu;
        xu.p[0] = __builtin_amdgcn_cvt_pkrtz(xr[0], xr[1]);
        xu.p[1] = __builtin_amdgcn_cvt_pkrtz(xr[2], 0.f);
        xa = xu.v4;
      }
      tf[g][0] = relupk(__builtin_amdgcn_mfma_f32_16x16x16f16(xa, w0, bi0, 0, 0, 0));
      tf[g][1] = relupk(__builtin_amdgcn_mfma_f32_16x16x16f16(xa, w1, bi1, 0, 0, 0));
    }
  }

  // ---- layers 0,1: G (aggregate) then L (MLP via folded Meff) ----
#pragma unroll
  for (int l = 0; l < 2; ++l) {
    // G: P^T[fout t][node_i gi] = sum_jt mfma(A=tf[jt][t] (transpose), B=adj tile)
#pragma unroll
    for (int gi = 0; gi < 8; ++gi) {
      f32x4 a0 = zero, a1 = zero;
#pragma unroll
      for (int p = 0; p < 4; ++p) {
        const half8 pair = *(const half8*)(adjb + ((gi * 4 + p) * 64 + lane) * 8);
        union { half8 v8; half4 h[2]; } pu; pu.v8 = pair;
        a0 = __builtin_amdgcn_mfma_f32_16x16x16f16(tf[2 * p][0],     pu.h[0], a0, 0, 0, 0);
        a1 = __builtin_amdgcn_mfma_f32_16x16x16f16(tf[2 * p][1],     pu.h[0], a1, 0, 0, 0);
        a0 = __builtin_amdgcn_mfma_f32_16x16x16f16(tf[2 * p + 1][0], pu.h[1], a0, 0, 0, 0);
        a1 = __builtin_amdgcn_mfma_f32_16x16x16f16(tf[2 * p + 1][1], pu.h[1], a1, 0, 0, 0);
      }
      pf[0][gi] = pkc(a0);
      pf[1][gi] = pkc(a1);
    }
    if (l == 1) break;

    // L1: T1[node][fout'] = relu(sum_t mfma(A=pf[t][g] (transpose), B=Meff tile) + c)
    {
      const f16* mbl = mb + 0 * 1024;   // l=0 -> Meff_1
      const half4 m00 = *(const half4*)(mbl + ((0 * 2 + 0) * 64 + lane) * 4);
      const half4 m01 = *(const half4*)(mbl + ((0 * 2 + 1) * 64 + lane) * 4);
      const half4 m10 = *(const half4*)(mbl + ((1 * 2 + 0) * 64 + lane) * 4);
      const half4 m11 = *(const half4*)(mbl + ((1 * 2 + 1) * 64 + lane) * 4);
      const float bb0 = bia[H + lrow], bb1 = bia[H + 16 + lrow];
      const f32x4 bi0 = {bb0, bb0, bb0, bb0};
      const f32x4 bi1 = {bb1, bb1, bb1, bb1};
#pragma unroll
      for (int g = 0; g < 8; ++g) {
        f32x4 c0 = __builtin_amdgcn_mfma_f32_16x16x16f16(pf[0][g], m00, bi0, 0, 0, 0);
        c0       = __builtin_amdgcn_mfma_f32_16x16x16f16(pf[1][g], m10, c0, 0, 0, 0);
        f32x4 c1 = __builtin_amdgcn_mfma_f32_16x16x16f16(pf[0][g], m01, bi1, 0, 0, 0);
        c1       = __builtin_amdgcn_mfma_f32_16x16x16f16(pf[1][g], m11, c1, 0, 0, 0);
        tf[g][0] = relupk(c0);
        tf[g][1] = relupk(c1);
      }
    }
  }

  // ---- L2 + folded readout: out = sum relu(P1·M2 + c2)[n][f]·v[n]·u[f] + cp
  {
    const f16* mbl = mb + 1 * 1024;   // Meff_2
    const half4 m00 = *(const half4*)(mbl + ((0 * 2 + 0) * 64 + lane) * 4);
    const half4 m01 = *(const half4*)(mbl + ((0 * 2 + 1) * 64 + lane) * 4);
    const half4 m10 = *(const half4*)(mbl + ((1 * 2 + 0) * 64 + lane) * 4);
    const half4 m11 = *(const half4*)(mbl + ((1 * 2 + 1) * 64 + lane) * 4);
    const float bb0 = bia[2 * H + lrow], bb1 = bia[2 * H + 16 + lrow];
    const f32x4 bi0 = {bb0, bb0, bb0, bb0};
    const f32x4 bi1 = {bb1, bb1, bb1, bb1};
    const float u0 = u[lrow], u1 = u[16 + lrow];
    float partial = 0.f;
#pragma unroll
    for (int g = 0; g < 8; ++g) {
      f32x4 c0 = __builtin_amdgcn_mfma_f32_16x16x16f16(pf[0][g], m00, bi0, 0, 0, 0);
      c0       = __builtin_amdgcn_mfma_f32_16x16x16f16(pf[1][g], m10, c0, 0, 0, 0);
      f32x4 c1 = __builtin_amdgcn_mfma_f32_16x16x16f16(pf[0][g], m01, bi1, 0, 0, 0);
      c1       = __builtin_amdgcn_mfma_f32_16x16x16f16(pf[1][g], m11, c1, 0, 0, 0);
      const float4 vv = *(const float4*)(v + g * 16 + quad * 4);   // v[node rows]
      partial += (fmaxf(c0[0], 0.f) * vv.x + fmaxf(c0[1], 0.f) * vv.y +
                  fmaxf(c0[2], 0.f) * vv.z + fmaxf(c0[3], 0.f) * vv.w) * u0 +
                 (fmaxf(c1[0], 0.f) * vv.x + fmaxf(c1[1], 0.f) * vv.y +
                  fmaxf(c1[2], 0.f) * vv.z + fmaxf(c1[3], 0.f) * vv.w) * u1;
    }
#pragma unroll
    for (int off = 32; off > 0; off >>= 1) partial += __shfl_down(partial, off, 64);
    if (lane == 0) out[b] = partial + cp[0];
  }
}

extern "C" void kernel_launch(void* const* d_in, const int* in_sizes, int n_in,
                              void* d_out, int out_size, void* d_ws, size_t ws_size,
                              hipStream_t stream) {
  const float* x      = (const float*)d_in[0];
  const float* adj    = (const float*)d_in[1];
  const float* W_lift = (const float*)d_in[2];
  const float* b_lift = (const float*)d_in[3];
  const float* W1     = (const float*)d_in[4];
  const float* b1     = (const float*)d_in[5];
  const float* W2     = (const float*)d_in[6];
  const float* b2     = (const float*)d_in[7];
  const float* W_ro   = (const float*)d_in[8];
  const float* b_ro   = (const float*)d_in[9];
  char* ws = (char*)d_ws;
  float* o = (float*)d_out;

  const int B = in_sizes[0] / (N * 3);   // 16384
  hipLaunchKernelGGL(prep, dim3(1), dim3(256), 0, stream,
                     adj, W_lift, b_lift, W1, b1, W2, b2, W_ro, b_ro, ws);
  hipLaunchKernelGGL(gnn_mfma, dim3(B / 4), dim3(256), 0, stream,
                     x, (const char*)ws, o);
}